// Round 1
// baseline (582.181 us; speedup 1.0000x reference)
//
#include <hip/hip_runtime.h>

#define B_ 2
#define S_ 2048
#define D_ 2048
#define H_ 16
#define DH_ 128
#define E3_ (3*D_)

typedef __attribute__((ext_vector_type(4))) float f32x4;
typedef __attribute__((ext_vector_type(8))) short bf16x8;

__device__ __forceinline__ unsigned short f2bf(float f) {
  unsigned u = __float_as_uint(f);
  u += 0x7fff + ((u >> 16) & 1);
  return (unsigned short)(u >> 16);
}
__device__ __forceinline__ float bf2f(unsigned short h) {
  return __uint_as_float(((unsigned)h) << 16);
}

__global__ void cast_f32_bf16(const float* __restrict__ in, unsigned short* __restrict__ out, int n4) {
  int i = blockIdx.x * 256 + threadIdx.x;
  if (i >= n4) return;
  float4 v = reinterpret_cast<const float4*>(in)[i];
  ushort4 o;
  o.x = f2bf(v.x); o.y = f2bf(v.y); o.z = f2bf(v.z); o.w = f2bf(v.w);
  reinterpret_cast<ushort4*>(out)[i] = o;
}

// C = A @ B^T.  A: [M,K] bf16 row-major, B: [N,K] bf16 row-major.
// 128x128 tile, BK=64, 4 waves (2x2), each wave 64x64 via 4x4 16x16x32 MFMA.
// LDS staged with global_load_lds (linear dest) + XOR-swizzled source, swizzled read.
template<typename OutT>
__global__ __launch_bounds__(256) void gemm_bt(const unsigned short* __restrict__ A,
                                               const unsigned short* __restrict__ Bm,
                                               OutT* __restrict__ C,
                                               int Mdim, int Ndim, int Kdim) {
  __shared__ __align__(16) unsigned short As[128*64];
  __shared__ __align__(16) unsigned short Bs[128*64];
  const int t = threadIdx.x;
  const int lane = t & 63;
  const int w = t >> 6;
  const int wm = w >> 1, wn = w & 1;
  const int l16 = lane & 15, lg = lane >> 4;
  const int bm = blockIdx.y, bn = blockIdx.x;

  f32x4 acc[4][4] = {};
  const int e0 = t * 8;

  for (int k0 = 0; k0 < Kdim; k0 += 64) {
#pragma unroll
    for (int it = 0; it < 4; ++it) {
      int e = e0 + it * 2048;
      int row = e >> 6;
      int g = (e >> 3) & 7;
      int gs = g ^ (row & 7);   // pre-swizzle the SOURCE (LDS dest stays linear)
      const unsigned short* ga = A  + (size_t)(bm*128 + row) * Kdim + k0 + gs*8;
      const unsigned short* gb = Bm + (size_t)(bn*128 + row) * Kdim + k0 + gs*8;
      __builtin_amdgcn_global_load_lds((const __attribute__((address_space(1))) unsigned int*)ga,
                                       (__attribute__((address_space(3))) unsigned int*)(&As[e]), 16, 0, 0);
      __builtin_amdgcn_global_load_lds((const __attribute__((address_space(1))) unsigned int*)gb,
                                       (__attribute__((address_space(3))) unsigned int*)(&Bs[e]), 16, 0, 0);
    }
    __syncthreads();
#pragma unroll
    for (int kk = 0; kk < 2; ++kk) {
      bf16x8 a[4], b[4];
#pragma unroll
      for (int mi = 0; mi < 4; ++mi) {
        int row = wm*64 + mi*16 + l16;
        int gw = kk*4 + lg;
        a[mi] = *reinterpret_cast<const bf16x8*>(&As[row*64 + ((gw ^ (row & 7))<<3)]);
      }
#pragma unroll
      for (int ni = 0; ni < 4; ++ni) {
        int row = wn*64 + ni*16 + l16;
        int gw = kk*4 + lg;
        b[ni] = *reinterpret_cast<const bf16x8*>(&Bs[row*64 + ((gw ^ (row & 7))<<3)]);
      }
#pragma unroll
      for (int mi = 0; mi < 4; ++mi)
#pragma unroll
        for (int ni = 0; ni < 4; ++ni)
          acc[mi][ni] = __builtin_amdgcn_mfma_f32_16x16x32_bf16(a[mi], b[ni], acc[mi][ni], 0, 0, 0);
    }
    __syncthreads();
  }
#pragma unroll
  for (int mi = 0; mi < 4; ++mi) {
#pragma unroll
    for (int ni = 0; ni < 4; ++ni) {
      int col = bn*128 + wn*64 + ni*16 + l16;
      int row0 = bm*128 + wm*64 + mi*16 + lg*4;
#pragma unroll
      for (int r = 0; r < 4; ++r) {
        float v = acc[mi][ni][r];
        size_t idx = (size_t)(row0 + r) * Ndim + col;
        if constexpr (sizeof(OutT) == 2) C[idx] = f2bf(v);
        else C[idx] = v;
      }
    }
  }
}

// RoPE on q and k parts of qkv, writing Q,K in [B,H,S,DH] bf16.
__global__ void rope_qk(const unsigned short* __restrict__ qkv,
                        const float* __restrict__ cosT, const float* __restrict__ sinT,
                        unsigned short* __restrict__ Q, unsigned short* __restrict__ K) {
  int d = threadIdx.x;          // 0..127
  int h = blockIdx.x;           // 0..15
  int s = blockIdx.y;           // 0..2047
  int b = blockIdx.z;           // 0..1
  size_t rowb = ((size_t)(b*S_ + s)) * E3_;
  int j = d >> 1;
  float c  = cosT[s*64 + j];
  float sn = sinT[s*64 + j];
  int de = d & ~1, odd = d & 1;
  float x0 = bf2f(qkv[rowb + h*DH_ + de]);
  float x1 = bf2f(qkv[rowb + h*DH_ + de + 1]);
  float oq = odd ? (x0*sn + x1*c) : (x0*c - x1*sn);
  size_t qo = (((size_t)(b*H_ + h)) * S_ + s) * DH_ + d;
  Q[qo] = f2bf(oq);
  float y0 = bf2f(qkv[rowb + D_ + h*DH_ + de]);
  float y1 = bf2f(qkv[rowb + D_ + h*DH_ + de + 1]);
  float ok = odd ? (y0*sn + y1*c) : (y0*c - y1*sn);
  K[qo] = f2bf(ok);
}

// V part of qkv -> Vt [B,H,DH,S] bf16 (transposed so PV B-frags are contiguous).
__global__ __launch_bounds__(256) void vtrans(const unsigned short* __restrict__ qkv,
                                              unsigned short* __restrict__ Vt) {
  __shared__ unsigned short tile[64*130];
  int s0 = blockIdx.x * 64;
  int h = blockIdx.y;
  int b = blockIdx.z;
  int t = threadIdx.x;
#pragma unroll
  for (int i = 0; i < 32; ++i) {
    int idx = i*256 + t;
    int sl = idx >> 7, d = idx & 127;
    tile[sl*130 + d] = qkv[((size_t)(b*S_ + s0 + sl)) * E3_ + 2*D_ + h*DH_ + d];
  }
  __syncthreads();
  size_t ob = ((size_t)(b*H_ + h)) * DH_ * S_;
#pragma unroll
  for (int i = 0; i < 32; ++i) {
    int idx = i*256 + t;
    int d = idx >> 6, sl = idx & 63;
    Vt[ob + (size_t)d * S_ + s0 + sl] = tile[sl*130 + d];
  }
}

// Flash attention, causal. 1 wave per block, 16 q-rows per block.
// Q frags in regs; K,V frags straight from global (L2-resident per head).
// P relayout (C-layout -> A-layout) through a small XOR-swizzled LDS buffer.
__global__ __launch_bounds__(64) void attn(const unsigned short* __restrict__ Q,
                                           const unsigned short* __restrict__ K,
                                           const unsigned short* __restrict__ Vt,
                                           unsigned short* __restrict__ O) {
  __shared__ __align__(16) unsigned short Plds[16*64];
  int q0 = blockIdx.x * 16;
  int bh = blockIdx.y;
  int b = bh >> 4, h = bh & 15;
  int lane = threadIdx.x;
  int l16 = lane & 15, lg = lane >> 4;
  const unsigned short* Qh = Q  + (size_t)bh * S_ * DH_;
  const unsigned short* Kh = K  + (size_t)bh * S_ * DH_;
  const unsigned short* Vh = Vt + (size_t)bh * DH_ * S_;
  bf16x8 aq[4];
#pragma unroll
  for (int kk = 0; kk < 4; ++kk)
    aq[kk] = *reinterpret_cast<const bf16x8*>(Qh + (size_t)(q0 + l16)*DH_ + kk*32 + lg*8);
  f32x4 o[8] = {};
  float mrun[4], lrun[4];
#pragma unroll
  for (int r = 0; r < 4; ++r) { mrun[r] = -1e30f; lrun[r] = 0.f; }
  const float scale = 0.08838834764831845f;

  for (int kv0 = 0; kv0 < q0 + 16; kv0 += 64) {
    f32x4 sc[4] = {};
#pragma unroll
    for (int kk = 0; kk < 4; ++kk) {
#pragma unroll
      for (int n = 0; n < 4; ++n) {
        bf16x8 bk = *reinterpret_cast<const bf16x8*>(Kh + (size_t)(kv0 + n*16 + l16)*DH_ + kk*32 + lg*8);
        sc[n] = __builtin_amdgcn_mfma_f32_16x16x32_bf16(aq[kk], bk, sc[n], 0, 0, 0);
      }
    }
    float sv[4][4];
    float mt[4] = {-1e30f,-1e30f,-1e30f,-1e30f};
#pragma unroll
    for (int n = 0; n < 4; ++n) {
      int col = kv0 + n*16 + l16;
#pragma unroll
      for (int r = 0; r < 4; ++r) {
        int rowq = q0 + lg*4 + r;
        float v = sc[n][r] * scale;
        v = (col > rowq) ? -1e30f : v;
        sv[n][r] = v;
        mt[r] = fmaxf(mt[r], v);
      }
    }
#pragma unroll
    for (int off = 1; off < 16; off <<= 1)
#pragma unroll
      for (int r = 0; r < 4; ++r)
        mt[r] = fmaxf(mt[r], __shfl_xor(mt[r], off));
    float alpha[4], rs[4] = {0.f,0.f,0.f,0.f};
#pragma unroll
    for (int r = 0; r < 4; ++r) {
      float mn = fmaxf(mrun[r], mt[r]);
      alpha[r] = __expf(mrun[r] - mn);
      mrun[r] = mn;
    }
#pragma unroll
    for (int n = 0; n < 4; ++n)
#pragma unroll
      for (int r = 0; r < 4; ++r) {
        float p = __expf(sv[n][r] - mrun[r]);
        sv[n][r] = p;
        rs[r] += p;
      }
#pragma unroll
    for (int off = 1; off < 16; off <<= 1)
#pragma unroll
      for (int r = 0; r < 4; ++r)
        rs[r] += __shfl_xor(rs[r], off);
#pragma unroll
    for (int r = 0; r < 4; ++r)
      lrun[r] = lrun[r]*alpha[r] + rs[r];
#pragma unroll
    for (int n2 = 0; n2 < 8; ++n2)
#pragma unroll
      for (int r = 0; r < 4; ++r)
        o[n2][r] *= alpha[r];
    // P -> LDS (swizzled), then read back as A-frags
#pragma unroll
    for (int n = 0; n < 4; ++n) {
#pragma unroll
      for (int r = 0; r < 4; ++r) {
        int rowp = lg*4 + r;
        int colp = n*16 + l16;
        int gp = colp >> 3, op = colp & 7;
        Plds[rowp*64 + ((gp ^ (rowp & 7))<<3) + op] = f2bf(sv[n][r]);
      }
    }
    __syncthreads();
    bf16x8 pa[2];
#pragma unroll
    for (int kk2 = 0; kk2 < 2; ++kk2) {
      int gw = kk2*4 + lg;
      pa[kk2] = *reinterpret_cast<const bf16x8*>(&Plds[l16*64 + ((gw ^ (l16 & 7))<<3)]);
    }
    __syncthreads();
#pragma unroll
    for (int kk2 = 0; kk2 < 2; ++kk2) {
#pragma unroll
      for (int n2 = 0; n2 < 8; ++n2) {
        bf16x8 bv = *reinterpret_cast<const bf16x8*>(Vh + (size_t)(n2*16 + l16)*S_ + kv0 + kk2*32 + lg*8);
        o[n2] = __builtin_amdgcn_mfma_f32_16x16x32_bf16(pa[kk2], bv, o[n2], 0, 0, 0);
      }
    }
  }
#pragma unroll
  for (int r = 0; r < 4; ++r) lrun[r] = 1.f / lrun[r];
  size_t ob = ((size_t)b * S_) * D_;
#pragma unroll
  for (int n2 = 0; n2 < 8; ++n2) {
#pragma unroll
    for (int r = 0; r < 4; ++r) {
      int rowq = q0 + lg*4 + r;
      int d = n2*16 + l16;
      O[ob + (size_t)rowq * D_ + h*DH_ + d] = f2bf(o[n2][r] * lrun[r]);
    }
  }
}

extern "C" void kernel_launch(void* const* d_in, const int* in_sizes, int n_in,
                              void* d_out, int out_size, void* d_ws, size_t ws_size,
                              hipStream_t stream) {
  const float* x    = (const float*)d_in[0];
  const float* fcos = (const float*)d_in[1];
  const float* fsin = (const float*)d_in[2];
  const float* wqkv = (const float*)d_in[4];
  const float* wo   = (const float*)d_in[5];
  float* out = (float*)d_out;
  char* ws = (char*)d_ws;

  unsigned short* xb    = (unsigned short*)(ws);                 // 16,777,216 B
  unsigned short* wqkvb = (unsigned short*)(ws + 16777216);      // 25,165,824 B
  unsigned short* wob   = (unsigned short*)(ws + 41943040);      //  8,388,608 B
  unsigned short* qkv   = (unsigned short*)(ws + 50331648);      // 50,331,648 B
  unsigned short* Qb    = (unsigned short*)(ws + 100663296);     // 16,777,216 B
  unsigned short* Kb    = (unsigned short*)(ws + 117440512);     // 16,777,216 B
  unsigned short* Vtb   = (unsigned short*)(ws + 134217728);     // 16,777,216 B (end 150,994,944)
  unsigned short* attn_out = xb;  // xb dead after gemm1 -> reuse

  cast_f32_bf16<<<dim3(2097152/256), 256, 0, stream>>>(x, xb, 2097152);
  cast_f32_bf16<<<dim3(3145728/256), 256, 0, stream>>>(wqkv, wqkvb, 3145728);
  cast_f32_bf16<<<dim3(1048576/256), 256, 0, stream>>>(wo, wob, 1048576);

  gemm_bt<unsigned short><<<dim3(6144/128, 4096/128), 256, 0, stream>>>(xb, wqkvb, qkv, 4096, 6144, 2048);
  rope_qk<<<dim3(16, 2048, 2), 128, 0, stream>>>(qkv, fcos, fsin, Qb, Kb);
  vtrans<<<dim3(32, 16, 2), 256, 0, stream>>>(qkv, Vtb);
  attn<<<dim3(128, 32), 64, 0, stream>>>(Qb, Kb, Vtb, attn_out);
  gemm_bt<float><<<dim3(2048/128, 4096/128), 256, 0, stream>>>(attn_out, wob, out, 4096, 2048, 2048);
}

// Round 2
// 391.103 us; speedup vs baseline: 1.4886x; 1.4886x over previous
//
#include <hip/hip_runtime.h>

#define B_ 2
#define S_ 2048
#define D_ 2048
#define H_ 16
#define DH_ 128
#define E3_ (3*D_)

typedef __attribute__((ext_vector_type(4))) float f32x4;
typedef __attribute__((ext_vector_type(8))) short bf16x8;

__device__ __forceinline__ unsigned short f2bf(float f) {
  unsigned u = __float_as_uint(f);
  u += 0x7fff + ((u >> 16) & 1);
  return (unsigned short)(u >> 16);
}
__device__ __forceinline__ float bf2f(unsigned short h) {
  return __uint_as_float(((unsigned)h) << 16);
}

__global__ void cast_f32_bf16(const float* __restrict__ in, unsigned short* __restrict__ out, int n4) {
  int i = blockIdx.x * 256 + threadIdx.x;
  if (i >= n4) return;
  float4 v = reinterpret_cast<const float4*>(in)[i];
  ushort4 o;
  o.x = f2bf(v.x); o.y = f2bf(v.y); o.z = f2bf(v.z); o.w = f2bf(v.w);
  reinterpret_cast<ushort4*>(out)[i] = o;
}

// C = A @ B^T.  A: [M,K] bf16 row-major, B: [N,K] bf16 row-major.
// 128x128 tile, BK=64, 4 waves (2x2), each wave 64x64 via 4x4 16x16x32 MFMA.
// LDS staged with global_load_lds (linear dest) + XOR-swizzled source, swizzled read.
template<typename OutT>
__global__ __launch_bounds__(256) void gemm_bt(const unsigned short* __restrict__ A,
                                               const unsigned short* __restrict__ Bm,
                                               OutT* __restrict__ C,
                                               int Mdim, int Ndim, int Kdim) {
  __shared__ __align__(16) unsigned short As[128*64];
  __shared__ __align__(16) unsigned short Bs[128*64];
  const int t = threadIdx.x;
  const int lane = t & 63;
  const int w = t >> 6;
  const int wm = w >> 1, wn = w & 1;
  const int l16 = lane & 15, lg = lane >> 4;
  const int bm = blockIdx.y, bn = blockIdx.x;

  f32x4 acc[4][4] = {};
  const int e0 = t * 8;

  for (int k0 = 0; k0 < Kdim; k0 += 64) {
#pragma unroll
    for (int it = 0; it < 4; ++it) {
      int e = e0 + it * 2048;
      int row = e >> 6;
      int g = (e >> 3) & 7;
      int gs = g ^ (row & 7);   // pre-swizzle the SOURCE (LDS dest stays linear)
      const unsigned short* ga = A  + (size_t)(bm*128 + row) * Kdim + k0 + gs*8;
      const unsigned short* gb = Bm + (size_t)(bn*128 + row) * Kdim + k0 + gs*8;
      __builtin_amdgcn_global_load_lds((const __attribute__((address_space(1))) unsigned int*)ga,
                                       (__attribute__((address_space(3))) unsigned int*)(&As[e]), 16, 0, 0);
      __builtin_amdgcn_global_load_lds((const __attribute__((address_space(1))) unsigned int*)gb,
                                       (__attribute__((address_space(3))) unsigned int*)(&Bs[e]), 16, 0, 0);
    }
    __syncthreads();
#pragma unroll
    for (int kk = 0; kk < 2; ++kk) {
      bf16x8 a[4], b[4];
#pragma unroll
      for (int mi = 0; mi < 4; ++mi) {
        int row = wm*64 + mi*16 + l16;
        int gw = kk*4 + lg;
        a[mi] = *reinterpret_cast<const bf16x8*>(&As[row*64 + ((gw ^ (row & 7))<<3)]);
      }
#pragma unroll
      for (int ni = 0; ni < 4; ++ni) {
        int row = wn*64 + ni*16 + l16;
        int gw = kk*4 + lg;
        b[ni] = *reinterpret_cast<const bf16x8*>(&Bs[row*64 + ((gw ^ (row & 7))<<3)]);
      }
#pragma unroll
      for (int mi = 0; mi < 4; ++mi)
#pragma unroll
        for (int ni = 0; ni < 4; ++ni)
          acc[mi][ni] = __builtin_amdgcn_mfma_f32_16x16x32_bf16(a[mi], b[ni], acc[mi][ni], 0, 0, 0);
    }
    __syncthreads();
  }
#pragma unroll
  for (int mi = 0; mi < 4; ++mi) {
#pragma unroll
    for (int ni = 0; ni < 4; ++ni) {
      int col = bn*128 + wn*64 + ni*16 + l16;
      int row0 = bm*128 + wm*64 + mi*16 + lg*4;
#pragma unroll
      for (int r = 0; r < 4; ++r) {
        float v = acc[mi][ni][r];
        size_t idx = (size_t)(row0 + r) * Ndim + col;
        if constexpr (sizeof(OutT) == 2) C[idx] = f2bf(v);
        else C[idx] = v;
      }
    }
  }
}

// RoPE on q and k parts of qkv, writing Q,K in [B,H,S,DH] bf16.
__global__ void rope_qk(const unsigned short* __restrict__ qkv,
                        const float* __restrict__ cosT, const float* __restrict__ sinT,
                        unsigned short* __restrict__ Q, unsigned short* __restrict__ K) {
  int d = threadIdx.x;          // 0..127
  int h = blockIdx.x;           // 0..15
  int s = blockIdx.y;           // 0..2047
  int b = blockIdx.z;           // 0..1
  size_t rowb = ((size_t)(b*S_ + s)) * E3_;
  int j = d >> 1;
  float c  = cosT[s*64 + j];
  float sn = sinT[s*64 + j];
  int de = d & ~1, odd = d & 1;
  float x0 = bf2f(qkv[rowb + h*DH_ + de]);
  float x1 = bf2f(qkv[rowb + h*DH_ + de + 1]);
  float oq = odd ? (x0*sn + x1*c) : (x0*c - x1*sn);
  size_t qo = (((size_t)(b*H_ + h)) * S_ + s) * DH_ + d;
  Q[qo] = f2bf(oq);
  float y0 = bf2f(qkv[rowb + D_ + h*DH_ + de]);
  float y1 = bf2f(qkv[rowb + D_ + h*DH_ + de + 1]);
  float ok = odd ? (y0*sn + y1*c) : (y0*c - y1*sn);
  K[qo] = f2bf(ok);
}

// V part of qkv -> Vt [B,H,DH,S] bf16 (transposed so PV B-frags are contiguous).
__global__ __launch_bounds__(256) void vtrans(const unsigned short* __restrict__ qkv,
                                              unsigned short* __restrict__ Vt) {
  __shared__ unsigned short tile[64*130];
  int s0 = blockIdx.x * 64;
  int h = blockIdx.y;
  int b = blockIdx.z;
  int t = threadIdx.x;
#pragma unroll
  for (int i = 0; i < 32; ++i) {
    int idx = i*256 + t;
    int sl = idx >> 7, d = idx & 127;
    tile[sl*130 + d] = qkv[((size_t)(b*S_ + s0 + sl)) * E3_ + 2*D_ + h*DH_ + d];
  }
  __syncthreads();
  size_t ob = ((size_t)(b*H_ + h)) * DH_ * S_;
#pragma unroll
  for (int i = 0; i < 32; ++i) {
    int idx = i*256 + t;
    int d = idx >> 6, sl = idx & 63;
    Vt[ob + (size_t)d * S_ + s0 + sl] = tile[sl*130 + d];
  }
}

// Flash attention, causal. 4 waves/block, QBLK=64 (16 q-rows per wave).
// K tile [64][128] + Vt tile [128][64] staged in LDS via global_load_lds
// (linear dest, pre-swizzled source, swizzled read). P relayout per-wave LDS.
__global__ __launch_bounds__(256) void attn(const unsigned short* __restrict__ Q,
                                            const unsigned short* __restrict__ K,
                                            const unsigned short* __restrict__ Vt,
                                            unsigned short* __restrict__ O) {
  __shared__ __align__(16) unsigned short Ks[64*128];     // 16 KB
  __shared__ __align__(16) unsigned short Vs[128*64];     // 16 KB
  __shared__ __align__(16) unsigned short Plds[4][16*64]; // 8 KB
  const int q0b = blockIdx.x * 64;
  const int bh = blockIdx.y;
  const int b = bh >> 4, h = bh & 15;
  const int t = threadIdx.x;
  const int lane = t & 63;
  const int w = t >> 6;
  const int l16 = lane & 15, lg = lane >> 4;
  const int q0 = q0b + w * 16;
  const unsigned short* Qh = Q  + (size_t)bh * S_ * DH_;
  const unsigned short* Kh = K  + (size_t)bh * S_ * DH_;
  const unsigned short* Vh = Vt + (size_t)bh * DH_ * S_;

  bf16x8 aq[4];
#pragma unroll
  for (int kk = 0; kk < 4; ++kk)
    aq[kk] = *reinterpret_cast<const bf16x8*>(Qh + (size_t)(q0 + l16)*DH_ + kk*32 + lg*8);

  f32x4 o[8] = {};
  float mrun[4], lrun[4];
#pragma unroll
  for (int r = 0; r < 4; ++r) { mrun[r] = -1e30f; lrun[r] = 0.f; }
  const float scale = 0.08838834764831845f;
  const int ntiles = blockIdx.x + 1;

  for (int tile = 0; tile < ntiles; ++tile) {
    const int kv0 = tile * 64;
    // stage K tile [64][128]: 8192 elems, 4 rounds of 256 thr x 8 elems
#pragma unroll
    for (int it = 0; it < 4; ++it) {
      int e = t*8 + it*2048;
      int row = e >> 7;              // 0..63
      int gslot = (e >> 3) & 15;     // 16 groups of 8 per row
      int gsrc = gslot ^ (row & 7);
      const unsigned short* ga = Kh + (size_t)(kv0 + row) * DH_ + gsrc*8;
      __builtin_amdgcn_global_load_lds((const __attribute__((address_space(1))) unsigned int*)ga,
                                       (__attribute__((address_space(3))) unsigned int*)(&Ks[e]), 16, 0, 0);
    }
    // stage V tile [128][64]
#pragma unroll
    for (int it = 0; it < 4; ++it) {
      int e = t*8 + it*2048;
      int d = e >> 6;                // 0..127
      int gslot = (e >> 3) & 7;      // 8 groups of 8 per row
      int gsrc = gslot ^ (d & 7);
      const unsigned short* gv = Vh + (size_t)d * S_ + kv0 + gsrc*8;
      __builtin_amdgcn_global_load_lds((const __attribute__((address_space(1))) unsigned int*)gv,
                                       (__attribute__((address_space(3))) unsigned int*)(&Vs[e]), 16, 0, 0);
    }
    __syncthreads();

    // QK^T from Ks
    f32x4 sc[4] = {};
#pragma unroll
    for (int kk = 0; kk < 4; ++kk) {
#pragma unroll
      for (int n = 0; n < 4; ++n) {
        int row = n*16 + l16;
        int g = kk*4 + lg;
        bf16x8 bk = *reinterpret_cast<const bf16x8*>(&Ks[row*128 + ((g ^ (row & 7))<<3)]);
        sc[n] = __builtin_amdgcn_mfma_f32_16x16x32_bf16(aq[kk], bk, sc[n], 0, 0, 0);
      }
    }
    float sv[4][4];
    float mt[4] = {-1e30f,-1e30f,-1e30f,-1e30f};
#pragma unroll
    for (int n = 0; n < 4; ++n) {
      int col = kv0 + n*16 + l16;
#pragma unroll
      for (int r = 0; r < 4; ++r) {
        int rowq = q0 + lg*4 + r;
        float v = sc[n][r] * scale;
        v = (col > rowq) ? -1e30f : v;
        sv[n][r] = v;
        mt[r] = fmaxf(mt[r], v);
      }
    }
#pragma unroll
    for (int off = 1; off < 16; off <<= 1)
#pragma unroll
      for (int r = 0; r < 4; ++r)
        mt[r] = fmaxf(mt[r], __shfl_xor(mt[r], off));
    float alpha[4], rs[4] = {0.f,0.f,0.f,0.f};
#pragma unroll
    for (int r = 0; r < 4; ++r) {
      float mn = fmaxf(mrun[r], mt[r]);
      alpha[r] = __expf(mrun[r] - mn);
      mrun[r] = mn;
    }
#pragma unroll
    for (int n = 0; n < 4; ++n)
#pragma unroll
      for (int r = 0; r < 4; ++r) {
        float p = __expf(sv[n][r] - mrun[r]);
        sv[n][r] = p;
        rs[r] += p;
      }
#pragma unroll
    for (int off = 1; off < 16; off <<= 1)
#pragma unroll
      for (int r = 0; r < 4; ++r)
        rs[r] += __shfl_xor(rs[r], off);
#pragma unroll
    for (int r = 0; r < 4; ++r)
      lrun[r] = lrun[r]*alpha[r] + rs[r];
#pragma unroll
    for (int n2 = 0; n2 < 8; ++n2)
#pragma unroll
      for (int r = 0; r < 4; ++r)
        o[n2][r] *= alpha[r];
    // P -> per-wave LDS (swizzled), read back as A-frags (no cross-wave sync needed)
    unsigned short* Pw = &Plds[w][0];
#pragma unroll
    for (int n = 0; n < 4; ++n) {
#pragma unroll
      for (int r = 0; r < 4; ++r) {
        int rowp = lg*4 + r;
        int colp = n*16 + l16;
        int gp = colp >> 3, op = colp & 7;
        Pw[rowp*64 + ((gp ^ (rowp & 7))<<3) + op] = f2bf(sv[n][r]);
      }
    }
    bf16x8 pa[2];
#pragma unroll
    for (int kk2 = 0; kk2 < 2; ++kk2) {
      int gw = kk2*4 + lg;
      pa[kk2] = *reinterpret_cast<const bf16x8*>(&Pw[l16*64 + ((gw ^ (l16 & 7))<<3)]);
    }
    // PV from Vs
#pragma unroll
    for (int kk2 = 0; kk2 < 2; ++kk2) {
#pragma unroll
      for (int n2 = 0; n2 < 8; ++n2) {
        int d = n2*16 + l16;
        int g = kk2*4 + lg;
        bf16x8 bv = *reinterpret_cast<const bf16x8*>(&Vs[d*64 + ((g ^ (d & 7))<<3)]);
        o[n2] = __builtin_amdgcn_mfma_f32_16x16x32_bf16(pa[kk2], bv, o[n2], 0, 0, 0);
      }
    }
    __syncthreads();
  }
#pragma unroll
  for (int r = 0; r < 4; ++r) lrun[r] = 1.f / lrun[r];
  size_t ob = ((size_t)b * S_) * D_;
#pragma unroll
  for (int n2 = 0; n2 < 8; ++n2) {
#pragma unroll
    for (int r = 0; r < 4; ++r) {
      int rowq = q0 + lg*4 + r;
      int d = n2*16 + l16;
      O[ob + (size_t)rowq * D_ + h*DH_ + d] = f2bf(o[n2][r] * lrun[r]);
    }
  }
}

extern "C" void kernel_launch(void* const* d_in, const int* in_sizes, int n_in,
                              void* d_out, int out_size, void* d_ws, size_t ws_size,
                              hipStream_t stream) {
  const float* x    = (const float*)d_in[0];
  const float* fcos = (const float*)d_in[1];
  const float* fsin = (const float*)d_in[2];
  const float* wqkv = (const float*)d_in[4];
  const float* wo   = (const float*)d_in[5];
  float* out = (float*)d_out;
  char* ws = (char*)d_ws;

  unsigned short* xb    = (unsigned short*)(ws);                 // 16,777,216 B
  unsigned short* wqkvb = (unsigned short*)(ws + 16777216);      // 25,165,824 B
  unsigned short* wob   = (unsigned short*)(ws + 41943040);      //  8,388,608 B
  unsigned short* qkv   = (unsigned short*)(ws + 50331648);      // 50,331,648 B
  unsigned short* Qb    = (unsigned short*)(ws + 100663296);     // 16,777,216 B
  unsigned short* Kb    = (unsigned short*)(ws + 117440512);     // 16,777,216 B
  unsigned short* Vtb   = (unsigned short*)(ws + 134217728);     // 16,777,216 B (end 150,994,944)
  unsigned short* attn_out = xb;  // xb dead after gemm1 -> reuse

  cast_f32_bf16<<<dim3(2097152/256), 256, 0, stream>>>(x, xb, 2097152);
  cast_f32_bf16<<<dim3(3145728/256), 256, 0, stream>>>(wqkv, wqkvb, 3145728);
  cast_f32_bf16<<<dim3(1048576/256), 256, 0, stream>>>(wo, wob, 1048576);

  gemm_bt<unsigned short><<<dim3(6144/128, 4096/128), 256, 0, stream>>>(xb, wqkvb, qkv, 4096, 6144, 2048);
  rope_qk<<<dim3(16, 2048, 2), 128, 0, stream>>>(qkv, fcos, fsin, Qb, Kb);
  vtrans<<<dim3(32, 16, 2), 256, 0, stream>>>(qkv, Vtb);
  attn<<<dim3(32, 32), 256, 0, stream>>>(Qb, Kb, Vtb, attn_out);
  gemm_bt<float><<<dim3(2048/128, 4096/128), 256, 0, stream>>>(attn_out, wob, out, 4096, 2048, 2048);
}

// Round 3
// 348.253 us; speedup vs baseline: 1.6717x; 1.1230x over previous
//
#include <hip/hip_runtime.h>

#define B_ 2
#define S_ 2048
#define D_ 2048
#define H_ 16
#define DH_ 128
#define E3_ (3*D_)

typedef __attribute__((ext_vector_type(4))) float f32x4;
typedef __attribute__((ext_vector_type(8))) short bf16x8;

__device__ __forceinline__ unsigned short f2bf(float f) {
  unsigned u = __float_as_uint(f);
  u += 0x7fff + ((u >> 16) & 1);
  return (unsigned short)(u >> 16);
}
__device__ __forceinline__ float bf2f(unsigned short h) {
  return __uint_as_float(((unsigned)h) << 16);
}

__global__ void cast_f32_bf16(const float* __restrict__ in, unsigned short* __restrict__ out, int n4) {
  int i = blockIdx.x * 256 + threadIdx.x;
  if (i >= n4) return;
  float4 v = reinterpret_cast<const float4*>(in)[i];
  ushort4 o;
  o.x = f2bf(v.x); o.y = f2bf(v.y); o.z = f2bf(v.z); o.w = f2bf(v.w);
  reinterpret_cast<ushort4*>(out)[i] = o;
}

// C = A @ B^T.  A: [M,K] bf16 row-major, B: [N,K] bf16 row-major.
// 128x128 tile, BK=64, 4 waves (2x2), each wave 64x64 via 4x4 16x16x32 MFMA.
// LDS staged with global_load_lds (linear dest) + XOR-swizzled source, swizzled read.
template<typename OutT>
__global__ __launch_bounds__(256) void gemm_bt(const unsigned short* __restrict__ A,
                                               const unsigned short* __restrict__ Bm,
                                               OutT* __restrict__ C,
                                               int Mdim, int Ndim, int Kdim) {
  __shared__ __align__(16) unsigned short As[128*64];
  __shared__ __align__(16) unsigned short Bs[128*64];
  const int t = threadIdx.x;
  const int lane = t & 63;
  const int w = t >> 6;
  const int wm = w >> 1, wn = w & 1;
  const int l16 = lane & 15, lg = lane >> 4;
  const int bm = blockIdx.y, bn = blockIdx.x;

  f32x4 acc[4][4] = {};
  const int e0 = t * 8;

  for (int k0 = 0; k0 < Kdim; k0 += 64) {
#pragma unroll
    for (int it = 0; it < 4; ++it) {
      int e = e0 + it * 2048;
      int row = e >> 6;
      int g = (e >> 3) & 7;
      int gs = g ^ (row & 7);   // pre-swizzle the SOURCE (LDS dest stays linear)
      const unsigned short* ga = A  + (size_t)(bm*128 + row) * Kdim + k0 + gs*8;
      const unsigned short* gb = Bm + (size_t)(bn*128 + row) * Kdim + k0 + gs*8;
      __builtin_amdgcn_global_load_lds((const __attribute__((address_space(1))) unsigned int*)ga,
                                       (__attribute__((address_space(3))) unsigned int*)(&As[e]), 16, 0, 0);
      __builtin_amdgcn_global_load_lds((const __attribute__((address_space(1))) unsigned int*)gb,
                                       (__attribute__((address_space(3))) unsigned int*)(&Bs[e]), 16, 0, 0);
    }
    __syncthreads();
#pragma unroll
    for (int kk = 0; kk < 2; ++kk) {
      bf16x8 a[4], b[4];
#pragma unroll
      for (int mi = 0; mi < 4; ++mi) {
        int row = wm*64 + mi*16 + l16;
        int gw = kk*4 + lg;
        a[mi] = *reinterpret_cast<const bf16x8*>(&As[row*64 + ((gw ^ (row & 7))<<3)]);
      }
#pragma unroll
      for (int ni = 0; ni < 4; ++ni) {
        int row = wn*64 + ni*16 + l16;
        int gw = kk*4 + lg;
        b[ni] = *reinterpret_cast<const bf16x8*>(&Bs[row*64 + ((gw ^ (row & 7))<<3)]);
      }
#pragma unroll
      for (int mi = 0; mi < 4; ++mi)
#pragma unroll
        for (int ni = 0; ni < 4; ++ni)
          acc[mi][ni] = __builtin_amdgcn_mfma_f32_16x16x32_bf16(a[mi], b[ni], acc[mi][ni], 0, 0, 0);
    }
    __syncthreads();
  }
#pragma unroll
  for (int mi = 0; mi < 4; ++mi) {
#pragma unroll
    for (int ni = 0; ni < 4; ++ni) {
      int col = bn*128 + wn*64 + ni*16 + l16;
      int row0 = bm*128 + wm*64 + mi*16 + lg*4;
#pragma unroll
      for (int r = 0; r < 4; ++r) {
        float v = acc[mi][ni][r];
        size_t idx = (size_t)(row0 + r) * Ndim + col;
        if constexpr (sizeof(OutT) == 2) C[idx] = f2bf(v);
        else C[idx] = v;
      }
    }
  }
}

// RoPE on q and k parts of qkv, writing Q,K in [B,H,S,DH] bf16.
__global__ void rope_qk(const unsigned short* __restrict__ qkv,
                        const float* __restrict__ cosT, const float* __restrict__ sinT,
                        unsigned short* __restrict__ Q, unsigned short* __restrict__ K) {
  int d = threadIdx.x;          // 0..127
  int h = blockIdx.x;           // 0..15
  int s = blockIdx.y;           // 0..2047
  int b = blockIdx.z;           // 0..1
  size_t rowb = ((size_t)(b*S_ + s)) * E3_;
  int j = d >> 1;
  float c  = cosT[s*64 + j];
  float sn = sinT[s*64 + j];
  int de = d & ~1, odd = d & 1;
  float x0 = bf2f(qkv[rowb + h*DH_ + de]);
  float x1 = bf2f(qkv[rowb + h*DH_ + de + 1]);
  float oq = odd ? (x0*sn + x1*c) : (x0*c - x1*sn);
  size_t qo = (((size_t)(b*H_ + h)) * S_ + s) * DH_ + d;
  Q[qo] = f2bf(oq);
  float y0 = bf2f(qkv[rowb + D_ + h*DH_ + de]);
  float y1 = bf2f(qkv[rowb + D_ + h*DH_ + de + 1]);
  float ok = odd ? (y0*sn + y1*c) : (y0*c - y1*sn);
  K[qo] = f2bf(ok);
}

// V part of qkv -> Vt [B,H,DH,S] bf16 (transposed so PV B-frags are contiguous).
__global__ __launch_bounds__(256) void vtrans(const unsigned short* __restrict__ qkv,
                                              unsigned short* __restrict__ Vt) {
  __shared__ unsigned short tile[64*130];
  int s0 = blockIdx.x * 64;
  int h = blockIdx.y;
  int b = blockIdx.z;
  int t = threadIdx.x;
#pragma unroll
  for (int i = 0; i < 32; ++i) {
    int idx = i*256 + t;
    int sl = idx >> 7, d = idx & 127;
    tile[sl*130 + d] = qkv[((size_t)(b*S_ + s0 + sl)) * E3_ + 2*D_ + h*DH_ + d];
  }
  __syncthreads();
  size_t ob = ((size_t)(b*H_ + h)) * DH_ * S_;
#pragma unroll
  for (int i = 0; i < 32; ++i) {
    int idx = i*256 + t;
    int d = idx >> 6, sl = idx & 63;
    Vt[ob + (size_t)d * S_ + s0 + sl] = tile[sl*130 + d];
  }
}

// Flash attention, causal. 8 waves/block, PAIRED q-tiles for load balance:
// waves 0-3 own q-tile x, waves 4-7 own q-tile (NQT-1-x); per-block work is
// uniform (33 tile-units). K/V tiles staged once in LDS, shared by both halves.
#define NQT 32
__global__ __launch_bounds__(512) void attn(const unsigned short* __restrict__ Q,
                                            const unsigned short* __restrict__ K,
                                            const unsigned short* __restrict__ Vt,
                                            unsigned short* __restrict__ O) {
  __shared__ __align__(16) unsigned short Ks[64*128];     // 16 KB
  __shared__ __align__(16) unsigned short Vs[128*64];     // 16 KB
  __shared__ __align__(16) unsigned short Plds[8][16*64]; // 16 KB
  const int x = blockIdx.x;            // 0..15
  const int bh = blockIdx.y;
  const int b = bh >> 4, h = bh & 15;
  const int t = threadIdx.x;
  const int lane = t & 63;
  const int w = t >> 6;                // 0..7
  const int wg = w >> 2;               // 0: tile a, 1: tile b
  const int wi = w & 3;
  const int l16 = lane & 15, lg = lane >> 4;
  const int qt = wg ? (NQT - 1 - x) : x;
  const int q0 = qt * 64 + wi * 16;
  const unsigned short* Qh = Q  + (size_t)bh * S_ * DH_;
  const unsigned short* Kh = K  + (size_t)bh * S_ * DH_;
  const unsigned short* Vh = Vt + (size_t)bh * DH_ * S_;

  bf16x8 aq[4];
#pragma unroll
  for (int kk = 0; kk < 4; ++kk)
    aq[kk] = *reinterpret_cast<const bf16x8*>(Qh + (size_t)(q0 + l16)*DH_ + kk*32 + lg*8);

  f32x4 o[8] = {};
  float mrun[4], lrun[4];
#pragma unroll
  for (int r = 0; r < 4; ++r) { mrun[r] = -1e30f; lrun[r] = 0.f; }
  // fold log2(e) into the scale: softmax computed in exp2 domain
  const float scale = 0.08838834764831845f * 1.4426950408889634f;
  const int ntiles = NQT - x;          // = max(x+1, NQT-x) since x < NQT/2

  for (int tile = 0; tile < ntiles; ++tile) {
    const int kv0 = tile * 64;
    // stage K tile [64][128]: 8192 elems, 2 rounds of 512 thr x 8 elems
#pragma unroll
    for (int it = 0; it < 2; ++it) {
      int e = t*8 + it*4096;
      int row = e >> 7;              // 0..63
      int gslot = (e >> 3) & 15;     // 16 groups of 8 per row
      int gsrc = gslot ^ (row & 7);
      const unsigned short* ga = Kh + (size_t)(kv0 + row) * DH_ + gsrc*8;
      __builtin_amdgcn_global_load_lds((const __attribute__((address_space(1))) unsigned int*)ga,
                                       (__attribute__((address_space(3))) unsigned int*)(&Ks[e]), 16, 0, 0);
    }
    // stage V tile [128][64]
#pragma unroll
    for (int it = 0; it < 2; ++it) {
      int e = t*8 + it*4096;
      int d = e >> 6;                // 0..127
      int gslot = (e >> 3) & 7;      // 8 groups of 8 per row
      int gsrc = gslot ^ (d & 7);
      const unsigned short* gv = Vh + (size_t)d * S_ + kv0 + gsrc*8;
      __builtin_amdgcn_global_load_lds((const __attribute__((address_space(1))) unsigned int*)gv,
                                       (__attribute__((address_space(3))) unsigned int*)(&Vs[e]), 16, 0, 0);
    }
    __syncthreads();

    if (tile <= qt) {   // wave-uniform guard: a-waves stop participating past their diagonal
      // QK^T from Ks
      f32x4 sc[4] = {};
#pragma unroll
      for (int kk = 0; kk < 4; ++kk) {
#pragma unroll
        for (int n = 0; n < 4; ++n) {
          int row = n*16 + l16;
          int g = kk*4 + lg;
          bf16x8 bk = *reinterpret_cast<const bf16x8*>(&Ks[row*128 + ((g ^ (row & 7))<<3)]);
          sc[n] = __builtin_amdgcn_mfma_f32_16x16x32_bf16(aq[kk], bk, sc[n], 0, 0, 0);
        }
      }
      float sv[4][4];
      float mt[4] = {-1e30f,-1e30f,-1e30f,-1e30f};
#pragma unroll
      for (int n = 0; n < 4; ++n) {
        int col = kv0 + n*16 + l16;
#pragma unroll
        for (int r = 0; r < 4; ++r) {
          int rowq = q0 + lg*4 + r;
          float v = sc[n][r] * scale;
          v = (col > rowq) ? -1e30f : v;
          sv[n][r] = v;
          mt[r] = fmaxf(mt[r], v);
        }
      }
#pragma unroll
      for (int off = 1; off < 16; off <<= 1)
#pragma unroll
        for (int r = 0; r < 4; ++r)
          mt[r] = fmaxf(mt[r], __shfl_xor(mt[r], off));
      float alpha[4], rs[4] = {0.f,0.f,0.f,0.f};
#pragma unroll
      for (int r = 0; r < 4; ++r) {
        float mn = fmaxf(mrun[r], mt[r]);
        alpha[r] = __builtin_amdgcn_exp2f(mrun[r] - mn);
        mrun[r] = mn;
      }
#pragma unroll
      for (int n = 0; n < 4; ++n)
#pragma unroll
        for (int r = 0; r < 4; ++r) {
          float p = __builtin_amdgcn_exp2f(sv[n][r] - mrun[r]);
          sv[n][r] = p;
          rs[r] += p;
        }
#pragma unroll
      for (int off = 1; off < 16; off <<= 1)
#pragma unroll
        for (int r = 0; r < 4; ++r)
          rs[r] += __shfl_xor(rs[r], off);
#pragma unroll
      for (int r = 0; r < 4; ++r)
        lrun[r] = lrun[r]*alpha[r] + rs[r];
#pragma unroll
      for (int n2 = 0; n2 < 8; ++n2)
#pragma unroll
        for (int r = 0; r < 4; ++r)
          o[n2][r] *= alpha[r];
      // P -> per-wave LDS (swizzled), read back as A-frags
      unsigned short* Pw = &Plds[w][0];
#pragma unroll
      for (int n = 0; n < 4; ++n) {
#pragma unroll
        for (int r = 0; r < 4; ++r) {
          int rowp = lg*4 + r;
          int colp = n*16 + l16;
          int gp = colp >> 3, op = colp & 7;
          Pw[rowp*64 + ((gp ^ (rowp & 7))<<3) + op] = f2bf(sv[n][r]);
        }
      }
      bf16x8 pa[2];
#pragma unroll
      for (int kk2 = 0; kk2 < 2; ++kk2) {
        int gw = kk2*4 + lg;
        pa[kk2] = *reinterpret_cast<const bf16x8*>(&Pw[l16*64 + ((gw ^ (l16 & 7))<<3)]);
      }
      // PV from Vs
#pragma unroll
      for (int kk2 = 0; kk2 < 2; ++kk2) {
#pragma unroll
        for (int n2 = 0; n2 < 8; ++n2) {
          int d = n2*16 + l16;
          int g = kk2*4 + lg;
          bf16x8 bv = *reinterpret_cast<const bf16x8*>(&Vs[d*64 + ((g ^ (d & 7))<<3)]);
          o[n2] = __builtin_amdgcn_mfma_f32_16x16x32_bf16(pa[kk2], bv, o[n2], 0, 0, 0);
        }
      }
    }
    __syncthreads();
  }
#pragma unroll
  for (int r = 0; r < 4; ++r) lrun[r] = 1.f / lrun[r];
  size_t ob = ((size_t)b * S_) * D_;
#pragma unroll
  for (int n2 = 0; n2 < 8; ++n2) {
#pragma unroll
    for (int r = 0; r < 4; ++r) {
      int rowq = q0 + lg*4 + r;
      int d = n2*16 + l16;
      O[ob + (size_t)rowq * D_ + h*DH_ + d] = f2bf(o[n2][r] * lrun[r]);
    }
  }
}

extern "C" void kernel_launch(void* const* d_in, const int* in_sizes, int n_in,
                              void* d_out, int out_size, void* d_ws, size_t ws_size,
                              hipStream_t stream) {
  const float* x    = (const float*)d_in[0];
  const float* fcos = (const float*)d_in[1];
  const float* fsin = (const float*)d_in[2];
  const float* wqkv = (const float*)d_in[4];
  const float* wo   = (const float*)d_in[5];
  float* out = (float*)d_out;
  char* ws = (char*)d_ws;

  unsigned short* xb    = (unsigned short*)(ws);                 // 16,777,216 B
  unsigned short* wqkvb = (unsigned short*)(ws + 16777216);      // 25,165,824 B
  unsigned short* wob   = (unsigned short*)(ws + 41943040);      //  8,388,608 B
  unsigned short* qkv   = (unsigned short*)(ws + 50331648);      // 50,331,648 B
  unsigned short* Qb    = (unsigned short*)(ws + 100663296);     // 16,777,216 B
  unsigned short* Kb    = (unsigned short*)(ws + 117440512);     // 16,777,216 B
  unsigned short* Vtb   = (unsigned short*)(ws + 134217728);     // 16,777,216 B (end 150,994,944)
  unsigned short* attn_out = xb;  // xb dead after gemm1 -> reuse

  cast_f32_bf16<<<dim3(2097152/256), 256, 0, stream>>>(x, xb, 2097152);
  cast_f32_bf16<<<dim3(3145728/256), 256, 0, stream>>>(wqkv, wqkvb, 3145728);
  cast_f32_bf16<<<dim3(1048576/256), 256, 0, stream>>>(wo, wob, 1048576);

  gemm_bt<unsigned short><<<dim3(6144/128, 4096/128), 256, 0, stream>>>(xb, wqkvb, qkv, 4096, 6144, 2048);
  rope_qk<<<dim3(16, 2048, 2), 128, 0, stream>>>(qkv, fcos, fsin, Qb, Kb);
  vtrans<<<dim3(32, 16, 2), 256, 0, stream>>>(qkv, Vtb);
  attn<<<dim3(16, 32), 512, 0, stream>>>(Qb, Kb, Vtb, attn_out);
  gemm_bt<float><<<dim3(2048/128, 4096/128), 256, 0, stream>>>(attn_out, wob, out, 4096, 2048, 2048);
}

// Round 4
// 271.244 us; speedup vs baseline: 2.1463x; 1.2839x over previous
//
#include <hip/hip_runtime.h>

#define B_ 2
#define S_ 2048
#define D_ 2048
#define H_ 16
#define DH_ 128
#define E3_ (3*D_)

typedef __attribute__((ext_vector_type(4))) float f32x4;
typedef __attribute__((ext_vector_type(8))) short bf16x8;

__device__ __forceinline__ unsigned short f2bf(float f) {
  unsigned u = __float_as_uint(f);
  u += 0x7fff + ((u >> 16) & 1);
  return (unsigned short)(u >> 16);
}
__device__ __forceinline__ float bf2f(unsigned short h) {
  return __uint_as_float(((unsigned)h) << 16);
}
__device__ __forceinline__ unsigned cvt_pk_bf16(float lo, float hi) {
  unsigned r;
  asm("v_cvt_pk_bf16_f32 %0, %1, %2" : "=v"(r) : "v"(lo), "v"(hi));
  return r;
}

__global__ void cast_f32_bf16(const float* __restrict__ in, unsigned short* __restrict__ out, int n4) {
  int i = blockIdx.x * 256 + threadIdx.x;
  if (i >= n4) return;
  float4 v = reinterpret_cast<const float4*>(in)[i];
  ushort4 o;
  o.x = f2bf(v.x); o.y = f2bf(v.y); o.z = f2bf(v.z); o.w = f2bf(v.w);
  reinterpret_cast<ushort4*>(out)[i] = o;
}

// C = A @ B^T.  A: [M,K] bf16 row-major, B: [N,K] bf16 row-major.
// 128x128 tile, BK=64, 4 waves (2x2), each wave 64x64 via 4x4 16x16x32 MFMA.
// If Vt != null and the block is in the V column range (bn >= 32), the
// epilogue writes transposed [b,h,d,s] directly (fused vtrans).
template<typename OutT>
__global__ __launch_bounds__(256) void gemm_bt(const unsigned short* __restrict__ A,
                                               const unsigned short* __restrict__ Bm,
                                               OutT* __restrict__ C,
                                               unsigned short* __restrict__ Vt,
                                               int Mdim, int Ndim, int Kdim) {
  __shared__ __align__(16) unsigned short As[128*64];
  __shared__ __align__(16) unsigned short Bs[128*64];
  const int t = threadIdx.x;
  const int lane = t & 63;
  const int w = t >> 6;
  const int wm = w >> 1, wn = w & 1;
  const int l16 = lane & 15, lg = lane >> 4;
  const int bm = blockIdx.y, bn = blockIdx.x;

  f32x4 acc[4][4] = {};
  const int e0 = t * 8;

  for (int k0 = 0; k0 < Kdim; k0 += 64) {
#pragma unroll
    for (int it = 0; it < 4; ++it) {
      int e = e0 + it * 2048;
      int row = e >> 6;
      int g = (e >> 3) & 7;
      int gs = g ^ (row & 7);   // pre-swizzle the SOURCE (LDS dest stays linear)
      const unsigned short* ga = A  + (size_t)(bm*128 + row) * Kdim + k0 + gs*8;
      const unsigned short* gb = Bm + (size_t)(bn*128 + row) * Kdim + k0 + gs*8;
      __builtin_amdgcn_global_load_lds((const __attribute__((address_space(1))) unsigned int*)ga,
                                       (__attribute__((address_space(3))) unsigned int*)(&As[e]), 16, 0, 0);
      __builtin_amdgcn_global_load_lds((const __attribute__((address_space(1))) unsigned int*)gb,
                                       (__attribute__((address_space(3))) unsigned int*)(&Bs[e]), 16, 0, 0);
    }
    __syncthreads();
#pragma unroll
    for (int kk = 0; kk < 2; ++kk) {
      bf16x8 a[4], b[4];
#pragma unroll
      for (int mi = 0; mi < 4; ++mi) {
        int row = wm*64 + mi*16 + l16;
        int gw = kk*4 + lg;
        a[mi] = *reinterpret_cast<const bf16x8*>(&As[row*64 + ((gw ^ (row & 7))<<3)]);
      }
#pragma unroll
      for (int ni = 0; ni < 4; ++ni) {
        int row = wn*64 + ni*16 + l16;
        int gw = kk*4 + lg;
        b[ni] = *reinterpret_cast<const bf16x8*>(&Bs[row*64 + ((gw ^ (row & 7))<<3)]);
      }
#pragma unroll
      for (int mi = 0; mi < 4; ++mi)
#pragma unroll
        for (int ni = 0; ni < 4; ++ni)
          acc[mi][ni] = __builtin_amdgcn_mfma_f32_16x16x32_bf16(a[mi], b[ni], acc[mi][ni], 0, 0, 0);
    }
    __syncthreads();
  }
  if constexpr (sizeof(OutT) == 2) {
    if (Vt != nullptr && bn >= 32) {
      // V block: write transposed to Vt[b][h][d][s] (fused vtrans)
#pragma unroll
      for (int mi = 0; mi < 4; ++mi) {
#pragma unroll
        for (int ni = 0; ni < 4; ++ni) {
          int colv = bn*128 + wn*64 + ni*16 + l16 - 2*D_;
          int h = colv >> 7, d = colv & 127;
          int row0 = bm*128 + wm*64 + mi*16 + lg*4;
          int b = row0 >> 11, s = row0 & 2047;
          ushort4 v4;
          v4.x = f2bf(acc[mi][ni][0]);
          v4.y = f2bf(acc[mi][ni][1]);
          v4.z = f2bf(acc[mi][ni][2]);
          v4.w = f2bf(acc[mi][ni][3]);
          *reinterpret_cast<ushort4*>(&Vt[(((size_t)(b*H_ + h))*DH_ + d)*S_ + s]) = v4;
        }
      }
      return;
    }
  }
#pragma unroll
  for (int mi = 0; mi < 4; ++mi) {
#pragma unroll
    for (int ni = 0; ni < 4; ++ni) {
      int col = bn*128 + wn*64 + ni*16 + l16;
      int row0 = bm*128 + wm*64 + mi*16 + lg*4;
#pragma unroll
      for (int r = 0; r < 4; ++r) {
        float v = acc[mi][ni][r];
        size_t idx = (size_t)(row0 + r) * Ndim + col;
        if constexpr (sizeof(OutT) == 2) C[idx] = f2bf(v);
        else C[idx] = v;
      }
    }
  }
}

// RoPE on q and k parts of qkv, writing Q,K in [B,H,S,DH] bf16.
// Q is pre-scaled by (1/sqrt(DH)) * log2(e) so attn runs in exp2 domain.
__global__ void rope_qk(const unsigned short* __restrict__ qkv,
                        const float* __restrict__ cosT, const float* __restrict__ sinT,
                        unsigned short* __restrict__ Q, unsigned short* __restrict__ K) {
  const float SCL = 0.08838834764831845f * 1.4426950408889634f;
  int d = threadIdx.x;          // 0..127
  int h = blockIdx.x;           // 0..15
  int s = blockIdx.y;           // 0..2047
  int b = blockIdx.z;           // 0..1
  size_t rowb = ((size_t)(b*S_ + s)) * E3_;
  int j = d >> 1;
  float c  = cosT[s*64 + j];
  float sn = sinT[s*64 + j];
  int de = d & ~1, odd = d & 1;
  float x0 = bf2f(qkv[rowb + h*DH_ + de]);
  float x1 = bf2f(qkv[rowb + h*DH_ + de + 1]);
  float oq = odd ? (x0*sn + x1*c) : (x0*c - x1*sn);
  size_t qo = (((size_t)(b*H_ + h)) * S_ + s) * DH_ + d;
  Q[qo] = f2bf(oq * SCL);
  float y0 = bf2f(qkv[rowb + D_ + h*DH_ + de]);
  float y1 = bf2f(qkv[rowb + D_ + h*DH_ + de + 1]);
  float ok = odd ? (y0*sn + y1*c) : (y0*c - y1*sn);
  K[qo] = f2bf(ok);
}

// Flash attention, causal. 8 waves/block, PAIRED q-tiles for load balance.
// SWAPPED QK^T: sc = mfma(K_frag, Q_frag) puts S^T in registers — lane
// (l16,lg) holds S[k=kv0+n*16+lg*4+r][q=q0+l16]; softmax state (mrun,lrun)
// is a per-lane scalar. P relayout: cvt_pk pairs -> swizzled per-wave LDS
// row [q][k] -> ds_read_b128 A-frags. Defer-rescale (THR=8, exp2 domain).
#define NQT 32
__global__ __launch_bounds__(512) void attn(const unsigned short* __restrict__ Q,
                                            const unsigned short* __restrict__ K,
                                            const unsigned short* __restrict__ Vt,
                                            unsigned short* __restrict__ O) {
  __shared__ __align__(16) unsigned short Ks[64*128];     // 16 KB
  __shared__ __align__(16) unsigned short Vs[128*64];     // 16 KB
  __shared__ __align__(16) unsigned short Plds[8][16*64]; // 16 KB
  const int x = blockIdx.x;            // 0..15
  const int bh = blockIdx.y;
  const int b = bh >> 4, h = bh & 15;
  const int t = threadIdx.x;
  const int lane = t & 63;
  const int w = t >> 6;                // 0..7
  const int wg = w >> 2;               // 0: tile a, 1: tile b
  const int wi = w & 3;
  const int l16 = lane & 15, lg = lane >> 4;
  const int qt = wg ? (NQT - 1 - x) : x;
  const int q0 = qt * 64 + wi * 16;
  const unsigned short* Qh = Q  + (size_t)bh * S_ * DH_;
  const unsigned short* Kh = K  + (size_t)bh * S_ * DH_;
  const unsigned short* Vh = Vt + (size_t)bh * DH_ * S_;

  bf16x8 aq[4];
#pragma unroll
  for (int kk = 0; kk < 4; ++kk)
    aq[kk] = *reinterpret_cast<const bf16x8*>(Qh + (size_t)(q0 + l16)*DH_ + kk*32 + lg*8);

  f32x4 o[8] = {};
  float mrun = -1e30f, lrun = 0.f;
  const int ntiles = NQT - x;          // = max(x+1, NQT-x) since x < NQT/2

  for (int tile = 0; tile < ntiles; ++tile) {
    const int kv0 = tile * 64;
    // stage K tile [64][128]: 8192 elems, 2 rounds of 512 thr x 8 elems
#pragma unroll
    for (int it = 0; it < 2; ++it) {
      int e = t*8 + it*4096;
      int row = e >> 7;              // 0..63
      int gslot = (e >> 3) & 15;     // 16 groups of 8 per row
      int gsrc = gslot ^ (row & 7);
      const unsigned short* ga = Kh + (size_t)(kv0 + row) * DH_ + gsrc*8;
      __builtin_amdgcn_global_load_lds((const __attribute__((address_space(1))) unsigned int*)ga,
                                       (__attribute__((address_space(3))) unsigned int*)(&Ks[e]), 16, 0, 0);
    }
    // stage V tile [128][64]
#pragma unroll
    for (int it = 0; it < 2; ++it) {
      int e = t*8 + it*4096;
      int d = e >> 6;                // 0..127
      int gslot = (e >> 3) & 7;      // 8 groups of 8 per row
      int gsrc = gslot ^ (d & 7);
      const unsigned short* gv = Vh + (size_t)d * S_ + kv0 + gsrc*8;
      __builtin_amdgcn_global_load_lds((const __attribute__((address_space(1))) unsigned int*)gv,
                                       (__attribute__((address_space(3))) unsigned int*)(&Vs[e]), 16, 0, 0);
    }
    __syncthreads();

    if (tile <= qt) {   // wave-uniform guard
      // S^T = K @ Q^T via swapped operands
      f32x4 sc[4] = {};
#pragma unroll
      for (int kk = 0; kk < 4; ++kk) {
#pragma unroll
        for (int n = 0; n < 4; ++n) {
          int row = n*16 + l16;
          int g = kk*4 + lg;
          bf16x8 bk = *reinterpret_cast<const bf16x8*>(&Ks[row*128 + ((g ^ (row & 7))<<3)]);
          sc[n] = __builtin_amdgcn_mfma_f32_16x16x32_bf16(bk, aq[kk], sc[n], 0, 0, 0);
        }
      }
      // sc[n][r] = S[k=kv0+n*16+lg*4+r][q=q0+l16] (already scaled, log2 units)
      if (tile == qt) {
        int qrow = q0 + l16;
#pragma unroll
        for (int n = 0; n < 4; ++n)
#pragma unroll
          for (int r = 0; r < 4; ++r) {
            int kidx = kv0 + n*16 + lg*4 + r;
            sc[n][r] = (kidx > qrow) ? -1e30f : sc[n][r];
          }
      }
      // row max: in-lane over 16, then across lg groups (lanes l16+16*lg)
      float mt = sc[0][0];
#pragma unroll
      for (int n = 0; n < 4; ++n)
#pragma unroll
        for (int r = 0; r < 4; ++r) mt = fmaxf(mt, sc[n][r]);
      mt = fmaxf(mt, __shfl_xor(mt, 16));
      mt = fmaxf(mt, __shfl_xor(mt, 32));
      // deferred rescale (THR = 8 in log2 units)
      if (__any(mt > mrun + 8.f)) {
        float mnew = fmaxf(mrun, mt);
        float alpha = __builtin_amdgcn_exp2f(mrun - mnew);
        mrun = mnew;
        lrun *= alpha;
        float ar[4];
#pragma unroll
        for (int r = 0; r < 4; ++r) ar[r] = __shfl(alpha, lg*4 + r);
#pragma unroll
        for (int n2 = 0; n2 < 8; ++n2)
#pragma unroll
          for (int r = 0; r < 4; ++r) o[n2][r] *= ar[r];
      }
      // P = exp2(S - mrun), row-sum, pack to bf16 pairs
      float rs = 0.f;
      unsigned pk[4][2];
#pragma unroll
      for (int n = 0; n < 4; ++n) {
        float p0 = __builtin_amdgcn_exp2f(sc[n][0] - mrun);
        float p1 = __builtin_amdgcn_exp2f(sc[n][1] - mrun);
        float p2 = __builtin_amdgcn_exp2f(sc[n][2] - mrun);
        float p3 = __builtin_amdgcn_exp2f(sc[n][3] - mrun);
        rs += (p0 + p1) + (p2 + p3);
        pk[n][0] = cvt_pk_bf16(p0, p1);
        pk[n][1] = cvt_pk_bf16(p2, p3);
      }
      rs += __shfl_xor(rs, 16);
      rs += __shfl_xor(rs, 32);
      lrun += rs;
      // write P^T rows into per-wave LDS [q=l16][k 0..63], pair-preserving XOR swizzle
      unsigned short* Pw = &Plds[w][0];
      char* Pb = (char*)Pw + l16*128;
#pragma unroll
      for (int n = 0; n < 4; ++n) {
        int sslot = (n*4 + lg) ^ (l16 & 14);
        *reinterpret_cast<uint2*>(Pb + sslot*8) = make_uint2(pk[n][0], pk[n][1]);
      }
      bf16x8 pa[2];
#pragma unroll
      for (int kk2 = 0; kk2 < 2; ++kk2) {
        int tp = (kk2*4 + lg) ^ ((l16 >> 1) & 7);
        pa[kk2] = *reinterpret_cast<const bf16x8*>(Pb + tp*16);
      }
      // PV from Vs
#pragma unroll
      for (int kk2 = 0; kk2 < 2; ++kk2) {
#pragma unroll
        for (int n2 = 0; n2 < 8; ++n2) {
          int d = n2*16 + l16;
          int g = kk2*4 + lg;
          bf16x8 bv = *reinterpret_cast<const bf16x8*>(&Vs[d*64 + ((g ^ (d & 7))<<3)]);
          o[n2] = __builtin_amdgcn_mfma_f32_16x16x32_bf16(pa[kk2], bv, o[n2], 0, 0, 0);
        }
      }
    }
    __syncthreads();
  }
  float linv = 1.f / lrun;
  float lr[4];
#pragma unroll
  for (int r = 0; r < 4; ++r) lr[r] = __shfl(linv, lg*4 + r);
  size_t ob = ((size_t)b * S_) * D_;
#pragma unroll
  for (int n2 = 0; n2 < 8; ++n2) {
#pragma unroll
    for (int r = 0; r < 4; ++r) {
      int rowq = q0 + lg*4 + r;
      int d = n2*16 + l16;
      O[ob + (size_t)rowq * D_ + h*DH_ + d] = f2bf(o[n2][r] * lr[r]);
    }
  }
}

extern "C" void kernel_launch(void* const* d_in, const int* in_sizes, int n_in,
                              void* d_out, int out_size, void* d_ws, size_t ws_size,
                              hipStream_t stream) {
  const float* x    = (const float*)d_in[0];
  const float* fcos = (const float*)d_in[1];
  const float* fsin = (const float*)d_in[2];
  const float* wqkv = (const float*)d_in[4];
  const float* wo   = (const float*)d_in[5];
  float* out = (float*)d_out;
  char* ws = (char*)d_ws;

  unsigned short* xb    = (unsigned short*)(ws);                 // 16,777,216 B
  unsigned short* wqkvb = (unsigned short*)(ws + 16777216);      // 25,165,824 B
  unsigned short* wob   = (unsigned short*)(ws + 41943040);      //  8,388,608 B
  unsigned short* qkv   = (unsigned short*)(ws + 50331648);      // 50,331,648 B
  unsigned short* Qb    = (unsigned short*)(ws + 100663296);     // 16,777,216 B
  unsigned short* Kb    = (unsigned short*)(ws + 117440512);     // 16,777,216 B
  unsigned short* Vtb   = (unsigned short*)(ws + 134217728);     // 16,777,216 B (end 150,994,944)
  unsigned short* attn_out = xb;  // xb dead after gemm1 -> reuse

  cast_f32_bf16<<<dim3(2097152/256), 256, 0, stream>>>(x, xb, 2097152);
  cast_f32_bf16<<<dim3(3145728/256), 256, 0, stream>>>(wqkv, wqkvb, 3145728);
  cast_f32_bf16<<<dim3(1048576/256), 256, 0, stream>>>(wo, wob, 1048576);

  gemm_bt<unsigned short><<<dim3(6144/128, 4096/128), 256, 0, stream>>>(xb, wqkvb, qkv, Vtb, 4096, 6144, 2048);
  rope_qk<<<dim3(16, 2048, 2), 128, 0, stream>>>(qkv, fcos, fsin, Qb, Kb);
  attn<<<dim3(16, 32), 512, 0, stream>>>(Qb, Kb, Vtb, attn_out);
  gemm_bt<float><<<dim3(2048/128, 4096/128), 256, 0, stream>>>(attn_out, wob, out, (unsigned short*)nullptr, 4096, 2048, 2048);
}